// Round 11
// baseline (519.218 us; speedup 1.0000x reference)
//
#include <hip/hip_runtime.h>

typedef unsigned short u16;
typedef unsigned int u32;
typedef __bf16 bf16x8 __attribute__((ext_vector_type(8)));
typedef float f32x4 __attribute__((ext_vector_type(4)));

#define S_    896
#define TR_   1643
#define NTOK_ 3286
#define MP_   3328   // 26*128 padded token rows

// ---------- helpers ----------
__device__ __forceinline__ u16 f2bf(float f) {
  u32 u = __builtin_bit_cast(u32, f);
  u = (u + 0x7FFFu + ((u >> 16) & 1u)) >> 16;   // RNE
  return (u16)u;
}

__device__ __forceinline__ void gload16(const void* g, void* l) {
  __builtin_amdgcn_global_load_lds(
      (const __attribute__((address_space(1))) u32*)g,
      (__attribute__((address_space(3))) u32*)l, 16, 0, 0);
}

// ---------- init ----------
__global__ void k_init(const int* __restrict__ index, int* __restrict__ inv,
                       float* __restrict__ xmean) {
  int i = blockIdx.x * 256 + threadIdx.x;
  if (i < TR_) inv[index[i]] = i;
  if (i < 6144) xmean[i] = 0.f;
}

// ---------- xmean ----------
__global__ void k_reduce_x(const float* __restrict__ x, float* __restrict__ xmean) {
  int i = blockIdx.x * 256 + threadIdx.x;
  int b = i / 3072, d = i % 3072;
  int s0 = blockIdx.y * 224;
  const float* p = x + (size_t)b * S_ * 3072 + (size_t)s0 * 3072 + d;
  float s = 0.f;
  for (int t = 0; t < 224; ++t) s += p[(size_t)t * 3072];
  atomicAdd(&xmean[i], s * (1.f / (float)S_));
}

// ---------- small gating ----------
__global__ __launch_bounds__(256)
void k_small_gates(const float* __restrict__ xmean,
                   const float* __restrict__ Wsel, const float* __restrict__ bsel,
                   const float* __restrict__ emb,  const float* __restrict__ Wemb,
                   const float* __restrict__ bemb,
                   float* __restrict__ w2buf, float* __restrict__ zpart,
                   float* __restrict__ outw) {
  __shared__ float red[256];
  __shared__ float gl[16];
  __shared__ float el[8];
  int tid = threadIdx.x;
  for (int o = 0; o < 16; ++o) {
    int b = o >> 3, g = o & 7;
    float s = 0.f;
    for (int d = tid; d < 3072; d += 256) s += xmean[b * 3072 + d] * Wsel[d * 8 + g];
    red[tid] = s; __syncthreads();
    for (int st = 128; st > 0; st >>= 1) { if (tid < st) red[tid] += red[tid + st]; __syncthreads(); }
    if (tid == 0) gl[o] = red[0] + bsel[g];
    __syncthreads();
  }
  for (int g = 0; g < 8; ++g) {
    float s = 0.f;
    for (int d = tid; d < 1536; d += 256) s += emb[d] * Wemb[d * 8 + g];
    red[tid] = s; __syncthreads();
    for (int st = 128; st > 0; st >>= 1) { if (tid < st) red[tid] += red[tid + st]; __syncthreads(); }
    if (tid == 0) el[g] = red[0] + bemb[g];
    __syncthreads();
  }
  if (tid == 0) {
    float zp = 0.f;
    for (int i = 0; i < 4; ++i) {
      float e0 = el[2 * i], e1 = el[2 * i + 1];
      float m = fmaxf(e0, e1);
      float x0 = expf(e0 - m), x1 = expf(e1 - m);
      float den = x0 + x1;
      float se0 = x0 / den, se1 = x1 / den;
      zp += (e0 * e0 + e1 * e1) * 0.5f;
      float tsq = 0.f;
      for (int b = 0; b < 2; ++b) {
        float t0 = gl[b * 8 + 2 * i], t1 = gl[b * 8 + 2 * i + 1];
        tsq += t0 * t0 + t1 * t1;
        float mm = fmaxf(t0, t1);
        float y0 = expf(t0 - mm), y1 = expf(t1 - mm);
        float dd = y0 + y1;
        float w0 = (y0 / dd + se0) * 0.5f, w1 = (y1 / dd + se1) * 0.5f;
        w2buf[b * 8 + 2 * i] = w0; w2buf[b * 8 + 2 * i + 1] = w1;
        outw[b * 8 + 2 * i]  = w0; outw[b * 8 + 2 * i + 1]  = w1;
      }
      zp += tsq * 0.25f;
    }
    *zpart = zp;
  }
}

// ---------- gather ----------
__global__ void k_gather(const float* __restrict__ out_in, const int* __restrict__ index,
                         float* __restrict__ o32, u16* __restrict__ obf,
                         float* __restrict__ gf) {
  int i = blockIdx.x * 256 + threadIdx.x;
  int n = i / S_, s = i % S_;
  float v = 0.f;
  if (n < NTOK_) {
    int b = n / TR_, t = n % TR_;
    v = out_in[((size_t)b * S_ + s) * TR_ + index[t]];
  } else if (s < 8) {
    gf[(size_t)n * 8 + s] = 0.f;
  }
  o32[i] = v;
  obf[i] = f2bf(v);
}

// ---------- per-token gating (no atomics, round-7 fix) ----------
__global__ __launch_bounds__(256)
void k_gates(const float* __restrict__ o32, const float* __restrict__ temb,
             const float* __restrict__ Wg, const float* __restrict__ bg,
             const float* __restrict__ w2buf, float* __restrict__ gf,
             float* __restrict__ zbuf) {
  int n = blockIdx.x;
  int b = n / TR_, t = n % TR_;
  int typ = (t < 228) ? 0 : (t < 519) ? 1 : (t < 1286) ? 2 : 3;
  int tid = threadIdx.x;
  const float* orow = o32 + (size_t)n * S_;
  const float* trow = temb + typ * S_;
  const float* W0 = Wg + (size_t)(2 * typ) * S_ * 8;

  float acc[16];
#pragma unroll
  for (int k = 0; k < 16; ++k) acc[k] = 0.f;
  for (int s = tid; s < S_; s += 256) {
    float ov = orow[s] + trow[s];
    const float4* wa = (const float4*)(W0 + s * 8);
    const float4* wb = (const float4*)(W0 + 7168 + s * 8);
    float4 a0 = wa[0], a1 = wa[1], b0 = wb[0], b1 = wb[1];
    acc[0]  += ov * a0.x; acc[1]  += ov * a0.y; acc[2]  += ov * a0.z; acc[3]  += ov * a0.w;
    acc[4]  += ov * a1.x; acc[5]  += ov * a1.y; acc[6]  += ov * a1.z; acc[7]  += ov * a1.w;
    acc[8]  += ov * b0.x; acc[9]  += ov * b0.y; acc[10] += ov * b0.z; acc[11] += ov * b0.w;
    acc[12] += ov * b1.x; acc[13] += ov * b1.y; acc[14] += ov * b1.z; acc[15] += ov * b1.w;
  }
#pragma unroll
  for (int k = 0; k < 16; ++k)
#pragma unroll
    for (int m = 1; m < 64; m <<= 1) acc[k] += __shfl_xor(acc[k], m, 64);

  __shared__ float wsum[4][16];
  __shared__ float lgsh[16];
  int w = tid >> 6, lane = tid & 63;
  if (lane == 0)
#pragma unroll
    for (int k = 0; k < 16; ++k) wsum[w][k] = acc[k];
  __syncthreads();
  if (tid < 16)
    lgsh[tid] = wsum[0][tid] + wsum[1][tid] + wsum[2][tid] + wsum[3][tid]
              + bg[(2 * typ + (tid >> 3)) * 8 + (tid & 7)];
  __syncthreads();

  if (tid == 0) {
    float g[8];
    for (int k = 0; k < 8; ++k) g[k] = 0.f;
    float zs[2];
    for (int j = 0; j < 2; ++j) {
      float l[8]; float ss = 0.f;
      for (int k = 0; k < 8; ++k) {
        float v = lgsh[j * 8 + k];
        v = v > 0.f ? v : 0.01f * v;
        l[k] = v; ss += v * v;
      }
      zs[j] = ss;
      int i0 = 0;
      for (int k = 1; k < 8; ++k) if (l[k] > l[i0]) i0 = k;
      int i1 = -1;
      for (int k = 0; k < 8; ++k) { if (k == i0) continue; if (i1 < 0 || l[k] > l[i1]) i1 = k; }
      int i2 = -1;
      for (int k = 0; k < 8; ++k) { if (k == i0 || k == i1) continue; if (i2 < 0 || l[k] > l[i2]) i2 = k; }
      float p1 = expf(l[i1] - l[i0]), p2 = expf(l[i2] - l[i0]);
      float den = 1.f + p1 + p2;
      float w2 = w2buf[b * 8 + 2 * typ + j];
      g[i0] += w2 / den; g[i1] += w2 * p1 / den; g[i2] += w2 * p2 / den;
    }
    float* gfp = gf + (size_t)n * 8;
    for (int k = 0; k < 8; ++k) gfp[k] = g[k];
    zbuf[n * 2 + 0] = zs[0];
    zbuf[n * 2 + 1] = zs[1];
  }
}

// ---------- segment reductions ----------
__global__ __launch_bounds__(256)
void k_reduce_gates(const float* __restrict__ gf, const float* __restrict__ zbuf,
                    float* __restrict__ allg, float* __restrict__ zsum) {
  __shared__ float red[256];
  const int s0a[4] = {0, 228, 519, 1286};
  const int cta[4] = {228, 291, 767, 357};
  int blk = blockIdx.x, tid = threadIdx.x;
  float s = 0.f;
  if (blk < 32) {
    int typ = blk >> 3, e = blk & 7;
    int s0 = s0a[typ], cnt = cta[typ];
    for (int i = tid; i < 2 * cnt; i += 256) {
      int bb = i / cnt, tt = s0 + i % cnt;
      s += gf[(size_t)(bb * TR_ + tt) * 8 + e];
    }
  } else {
    int idx = blk - 32, typ = idx >> 1, j = idx & 1;
    int s0 = s0a[typ], cnt = cta[typ];
    for (int i = tid; i < 2 * cnt; i += 256) {
      int bb = i / cnt, tt = s0 + i % cnt;
      s += zbuf[(size_t)(bb * TR_ + tt) * 2 + j];
    }
  }
  red[tid] = s; __syncthreads();
  for (int st = 128; st > 0; st >>= 1) { if (tid < st) red[tid] += red[tid + st]; __syncthreads(); }
  if (tid == 0) {
    if (blk < 32) allg[blk] = red[0];
    else          zsum[blk - 32] = red[0];
  }
}

// ---------- tiled transpose f32 -> bf16 with output-row padding ----------
__global__ __launch_bounds__(256)
void k_transpose(const float* __restrict__ W, u16* __restrict__ Wt,
                 int R, int C, int ldo, size_t eo) {
  __shared__ float tile[32][33];
  int e = blockIdx.z;
  const float* Wp = W + (size_t)e * R * C;
  u16* Wtp = Wt + (size_t)e * eo;
  int c0 = blockIdx.x * 32, r0 = blockIdx.y * 32;
  int tx = threadIdx.x & 31, ty = threadIdx.x >> 5;
  for (int i = ty; i < 32; i += 8)
    tile[i][tx] = (c0 + tx < C) ? Wp[(size_t)(r0 + i) * C + c0 + tx] : 0.f;
  __syncthreads();
  for (int i = ty; i < 32; i += 8) Wtp[(size_t)(c0 + i) * ldo + r0 + tx] = f2bf(tile[tx][i]);
}

// ---------- 256x256x64 8-wave counted-vmcnt GEMM, reads pipelined 1 quadrant ahead ----------
// Round-10 change: dedicated a0F/a1F register sets; READ_B1 issued BEFORE Q00's
// MFMA and READ_A1 before Q01's — compiler emits counted lgkmcnt (not 0), so the
// LDS unit streams the next quadrant's fragments UNDER the current MFMA cluster
// (LDS ~768cy/tile vs MFMA ~614cy/tile per CU: overlap is mandatory for >45% util).
// vmcnt counts unchanged (4/6/6; peel 4/2/0); each counted wait still precedes the
// barrier that publishes cross-wave staging.
template <int MODE>
__global__ __launch_bounds__(512, 2)
void k_gemm8(const u16* __restrict__ A, const u16* __restrict__ Bt,
             int K, int lda, int ldb,
             const float* __restrict__ gf, const float* __restrict__ bias,
             u16* __restrict__ H, float* __restrict__ ypart, int P) {
  __shared__ __align__(16) u16 lds[2 * 32768];   // [buf][A:16384|B:16384] u16
  const int tid = threadIdx.x;
  const int lane = tid & 63;
  const int wid = tid >> 6;
  const int wr = wid >> 2, wc = wid & 3;

  int bx, by, bz = 0;
  if (MODE == 1) {
    int f = blockIdx.y * 56 + blockIdx.x;            // 728 = 8*91
    f = (f & 7) * 91 + (f >> 3);
    by = f / 56; bx = f % 56;
  } else {
    int f = blockIdx.z * 52 + blockIdx.y * 4 + blockIdx.x;  // 52P, P even
    int n8 = (52 * P) >> 3;
    f = (f & 7) * n8 + (f >> 3);
    bz = f / 52; int r = f % 52;
    by = r / 4; bx = r % 4;
  }

  int kt0 = 0, ktN = K >> 6;
  if (MODE == 2) {
    int nt = K >> 6;
    kt0 = (bz * nt) / P; ktN = ((bz + 1) * nt) / P;
  }
  const int NT = ktN - kt0;

  const u16* Ag = A + (size_t)(by * 256) * lda;
  const u16* Bg = Bt + (size_t)(bx * 256) * ldb;

#define SA(buf, g, k0)                                                          \
  { _Pragma("unroll")                                                           \
    for (int q = 0; q < 2; ++q) {                                               \
      const int br = q * 128 + (g) * 64 + wid * 8;                              \
      const int row = br + (lane >> 3);                                         \
      gload16(Ag + (size_t)row * lda + (((lane & 7) ^ (lane >> 3)) << 3) + (k0),\
              lds + (buf) * 32768 + br * 64 + lane * 8);                        \
    } }
#define SB(buf, g, k0)                                                          \
  { _Pragma("unroll")                                                           \
    for (int q = 0; q < 2; ++q) {                                               \
      const int sI = q * 8 + wid;                                               \
      const int br = (sI >> 2) * 64 + (g) * 32 + (sI & 3) * 8;                  \
      const int row = br + (lane >> 3);                                         \
      gload16(Bg + (size_t)row * ldb + (((lane & 7) ^ (lane >> 3)) << 3) + (k0),\
              lds + (buf) * 32768 + 16384 + br * 64 + lane * 8);                \
    } }
#define PSYNC(N)                                             \
  asm volatile("s_waitcnt vmcnt(" #N ")" ::: "memory");      \
  __builtin_amdgcn_s_barrier();                              \
  __builtin_amdgcn_sched_barrier(0);

  const int l15 = lane & 15, l16 = lane >> 4, l7 = lane & 7;
  const int swz0 = (l16 ^ l7) << 3;
  const int swz1 = ((4 + l16) ^ l7) << 3;
  const int rA = (wr * 128 + l15) * 64;
  const int rB = (wc * 64 + l15) * 64;

  f32x4 acc[8][4] = {};
  bf16x8 a0F[4][2], a1F[4][2], b0F[2][2], b1F[2][2];

#define READ_A0  _Pragma("unroll") for (int i = 0; i < 4; ++i) {               \
    a0F[i][0] = *(const bf16x8*)(lA + rA + i * 1024 + swz0);                   \
    a0F[i][1] = *(const bf16x8*)(lA + rA + i * 1024 + swz1); }
#define READ_A1  _Pragma("unroll") for (int i = 0; i < 4; ++i) {               \
    a1F[i][0] = *(const bf16x8*)(lA + rA + (i + 4) * 1024 + swz0);             \
    a1F[i][1] = *(const bf16x8*)(lA + rA + (i + 4) * 1024 + swz1); }
#define READ_B0  _Pragma("unroll") for (int j = 0; j < 2; ++j) {               \
    b0F[j][0] = *(const bf16x8*)(lB + rB + j * 1024 + swz0);                   \
    b0F[j][1] = *(const bf16x8*)(lB + rB + j * 1024 + swz1); }
#define READ_B1  _Pragma("unroll") for (int j = 0; j < 2; ++j) {               \
    b1F[j][0] = *(const bf16x8*)(lB + rB + (j + 2) * 1024 + swz0);             \
    b1F[j][1] = *(const bf16x8*)(lB + rB + (j + 2) * 1024 + swz1); }
#define MFMA16(AF, IB, JB, BF)                                                 \
  __builtin_amdgcn_s_setprio(1);                                               \
  _Pragma("unroll") for (int i = 0; i < 4; ++i)                                \
  _Pragma("unroll") for (int j = 0; j < 2; ++j) {                              \
    acc[i + IB][j + JB] = __builtin_amdgcn_mfma_f32_16x16x32_bf16(AF[i][0], BF[j][0], acc[i + IB][j + JB], 0, 0, 0); \
    acc[i + IB][j + JB] = __builtin_amdgcn_mfma_f32_16x16x32_bf16(AF[i][1], BF[j][1], acc[i + IB][j + JB], 0, 0, 0); \
  }                                                                            \
  __builtin_amdgcn_s_setprio(0);

  // prologue: tile kt0, issue order A0,B0,B1,A1 (oldest -> newest)
  { const int k0 = kt0 << 6; SA(0, 0, k0) SB(0, 0, k0) SB(0, 1, k0) SA(0, 1, k0) }

  int cur = 0;
  for (int t = 0; t < NT - 1; ++t) {
    const u16* lA = lds + cur * 32768;
    const u16* lB = lA + 16384;
    const int nk0 = (kt0 + t + 1) << 6;
    // G1: wait A0,B0(t); stage A0,B0(t+1); read A0,B0
    PSYNC(4)
    SA(cur ^ 1, 0, nk0) SB(cur ^ 1, 0, nk0)
    READ_A0 READ_B0
    // G2: wait B1(t); stage B1(t+1); read B1 (streams under Q00)
    PSYNC(6)
    SB(cur ^ 1, 1, nk0)
    READ_B1
    MFMA16(a0F, 0, 0, b0F)
    // G3: wait A1(t); stage A1(t+1); read A1 (streams under Q01)
    PSYNC(6)
    SA(cur ^ 1, 1, nk0)
    READ_A1
    MFMA16(a0F, 0, 2, b1F)
    // register-only quadrants; staging drains underneath
    MFMA16(a1F, 4, 2, b1F)
    MFMA16(a1F, 4, 0, b0F)
    cur ^= 1;
  }
  // last tile: draining waits, same read-ahead shape
  {
    const u16* lA = lds + cur * 32768;
    const u16* lB = lA + 16384;
    PSYNC(4)
    READ_A0 READ_B0
    PSYNC(2)
    READ_B1
    MFMA16(a0F, 0, 0, b0F)
    PSYNC(0)
    READ_A1
    MFMA16(a0F, 0, 2, b1F)
    MFMA16(a1F, 4, 2, b1F)
    MFMA16(a1F, 4, 0, b0F)
  }
#undef SA
#undef SB
#undef PSYNC
#undef READ_A0
#undef READ_A1
#undef READ_B0
#undef READ_B1
#undef MFMA16

  // ---- epilogue ----
  if (MODE == 1) {
    const int e = bx / 7;                 // 1792 = 7*256: tile within one expert
#pragma unroll
    for (int j = 0; j < 4; ++j) {
      const int col = bx * 256 + wc * 64 + j * 16 + l15;
      const float bia = bias[col];
#pragma unroll
      for (int i = 0; i < 8; ++i)
#pragma unroll
        for (int r = 0; r < 4; ++r) {
          const int row = by * 256 + wr * 128 + i * 16 + l16 * 4 + r;
          float v = acc[i][j][r] + bia;
          v = v > 0.f ? v : 0.f;
          H[(size_t)row * 14336 + col] = f2bf(v * gf[row * 8 + e]);
        }
    }
  } else {
    float* yp = ypart + (size_t)bz * ((size_t)MP_ * 1024);
#pragma unroll
    for (int j = 0; j < 4; ++j) {
      const int col = bx * 256 + wc * 64 + j * 16 + l15;
#pragma unroll
      for (int i = 0; i < 8; ++i)
#pragma unroll
        for (int r = 0; r < 4; ++r) {
          const int row = by * 256 + wr * 128 + i * 16 + l16 * 4 + r;
          yp[(size_t)row * 1024 + col] = acc[i][j][r];
        }
    }
  }
}

// ---------- reduce split-K partials + gated b2 bias ----------
__global__ void k_reduce_y(const float* __restrict__ yp, int P,
                           const float* __restrict__ gf, const float* __restrict__ b2,
                           float* __restrict__ yout) {
  int i = blockIdx.x * 256 + threadIdx.x;   // < NTOK_*S_
  int n = i / S_, s = i % S_;
  float acc = 0.f;
  for (int p = 0; p < P; ++p) acc += yp[(size_t)p * ((size_t)MP_ * 1024) + (size_t)n * 1024 + s];
  const float* g = gf + (size_t)n * 8;
#pragma unroll
  for (int e = 0; e < 8; ++e) acc += g[e] * b2[e * S_ + s];
  yout[(size_t)n * S_ + s] = acc;
}

// ---------- scatter ----------
__global__ void k_scatter(const float* __restrict__ y, const float* __restrict__ out_in,
                          const int* __restrict__ inv, float* __restrict__ dout) {
  int i = blockIdx.x * 256 + threadIdx.x;
  int tr = i % TR_;
  int bs = i / TR_;
  int b = bs / S_, s = bs % S_;
  int t = inv[tr];
  dout[i] = out_in[i] + y[((size_t)b * TR_ + t) * S_ + s];
}

// ---------- finalize ----------
__global__ void k_finalize(const float* __restrict__ allg, const float* __restrict__ zsum,
                           const float* __restrict__ zpart, float* __restrict__ dout) {
  int tid = threadIdx.x;
  if (tid < 32) dout[2944256 + tid] = allg[tid];
  if (tid == 32) {
    float z = *zpart;
    const int Ts[4] = {228, 291, 767, 357};
    for (int i = 0; i < 4; ++i)
      for (int j = 0; j < 2; ++j)
        z += zsum[i * 2 + j] / (float)(2 * Ts[i] * 8);
    dout[2944288] = z;
    dout[2944289] = 0.f;
  }
}

extern "C" void kernel_launch(void* const* d_in, const int* in_sizes, int n_in,
                              void* d_out, int out_size, void* d_ws, size_t ws_size,
                              hipStream_t stream) {
  const float* x         = (const float*)d_in[0];
  const float* out_in    = (const float*)d_in[1];
  const float* embedding = (const float*)d_in[2];
  const int*   index     = (const int*)d_in[3];
  const float* Wsel      = (const float*)d_in[4];
  const float* bsel      = (const float*)d_in[5];
  const float* Wemb      = (const float*)d_in[6];
  const float* bemb      = (const float*)d_in[7];
  const float* Wg        = (const float*)d_in[8];
  const float* bg        = (const float*)d_in[9];
  const float* temb      = (const float*)d_in[10];
  const float* W1        = (const float*)d_in[11];
  const float* b1        = (const float*)d_in[12];
  const float* W2        = (const float*)d_in[13];
  const float* b2        = (const float*)d_in[14];
  float* dout = (float*)d_out;

  char* ws = (char*)d_ws;
  float* allg  = (float*)(ws + 0);
  float* zsum  = (float*)(ws + 128);
  float* zpart = (float*)(ws + 160);
  float* w2buf = (float*)(ws + 192);
  int*   inv   = (int*)(ws + 256);
  float* xmean = (float*)(ws + 8192);
  float* gf    = (float*)(ws + 32768);       // MP*8 f        -> ends 139264
  float* o32   = (float*)(ws + 139264);      // MP*896 f      -> ends 12066816 (reused as yb)
  float* yb    = o32;
  float* zbuf  = (float*)(ws + 139264 + (size_t)NTOK_ * S_ * 4);  // pad-row overlay
  u16*   obf   = (u16*)(ws + 12066816);      // MP*896 bf16   -> ends 18030592
  u16*   w1t   = (u16*)(ws + 18030592);      // 14336*896 bf16 -> ends 43720704
  u16*   w2t   = (u16*)(ws + 43720704);      // 1024*14336 bf16 (padded) -> ends 73080832
  u16*   Hb    = (u16*)(ws + 73080832);      // MP*14336 bf16  -> ends 168501248

  const size_t HIGH = 168501248ull, YPSZ = (size_t)MP_ * 1024 * 4;  // 13,631,488
  int P; float* ypart = (float*)(ws + HIGH);
  if      (ws_size >= HIGH + 8 * YPSZ) P = 8;
  else if (ws_size >= HIGH + 6 * YPSZ) P = 6;
  else if (ws_size >= HIGH + 4 * YPSZ) P = 4;
  else                                 P = 2;

  k_init<<<26, 256, 0, stream>>>(index, inv, xmean);
  k_reduce_x<<<dim3(24, 4), 256, 0, stream>>>(x, xmean);
  k_small_gates<<<1, 256, 0, stream>>>(xmean, Wsel, bsel, embedding, Wemb, bemb,
                                       w2buf, zpart, dout + 2944290);
  k_gather<<<11648, 256, 0, stream>>>(out_in, index, o32, obf, gf);
  k_gates<<<NTOK_, 256, 0, stream>>>(o32, temb, Wg, bg, w2buf, gf, zbuf);
  k_reduce_gates<<<40, 256, 0, stream>>>(gf, zbuf, allg, zsum);

  // GEMM1: H' = gf .* relu(obf @ W1^T + b1)   [M=3328, N=14336, K=896]
  k_transpose<<<dim3(56, 28, 8), 256, 0, stream>>>(W1, w1t, 896, 1792, 896, (size_t)1605632);
  k_gemm8<1><<<dim3(56, 13), 512, 0, stream>>>(
      obf, w1t, 896, 896, 896, gf, b1, Hb, nullptr, 0);

  // GEMM2: ypart[z] = H' @ W2flat^T chunk  [M=3328, N=896(pad 1024), K=14336 split-P]
  k_transpose<<<dim3(32, 56, 8), 256, 0, stream>>>(W2, w2t, 1792, 896, 14336, (size_t)1792);
  k_gemm8<2><<<dim3(4, 13, P), 512, 0, stream>>>(
      Hb, w2t, 14336, 14336, 14336, nullptr, nullptr, nullptr, ypart, P);
  k_reduce_y<<<11501, 256, 0, stream>>>(ypart, P, gf, b2, yb);

  k_scatter<<<11501, 256, 0, stream>>>(yb, out_in, inv, dout);
  k_finalize<<<1, 64, 0, stream>>>(allg, zsum, zpart, dout);
}

// Round 12
// 446.744 us; speedup vs baseline: 1.1622x; 1.1622x over previous
//
#include <hip/hip_runtime.h>

typedef unsigned short u16;
typedef unsigned int u32;
typedef __bf16 bf16x8 __attribute__((ext_vector_type(8)));
typedef float f32x4 __attribute__((ext_vector_type(4)));

#define S_    896
#define TR_   1643
#define NTOK_ 3286
#define MP_   3328   // 26*128 padded token rows

// ---------- helpers ----------
__device__ __forceinline__ u16 f2bf(float f) {
  u32 u = __builtin_bit_cast(u32, f);
  u = (u + 0x7FFFu + ((u >> 16) & 1u)) >> 16;   // RNE
  return (u16)u;
}

__device__ __forceinline__ void gload16(const void* g, void* l) {
  __builtin_amdgcn_global_load_lds(
      (const __attribute__((address_space(1))) u32*)g,
      (__attribute__((address_space(3))) u32*)l, 16, 0, 0);
}

// ---------- init: inv perm, xmean zero, pad-row zero (o32/obf/gf) ----------
// 147 blocks x 256 = 37632 threads == pad elements of o32/obf (rows 3286..3327).
__global__ void k_init(const int* __restrict__ index, int* __restrict__ inv,
                       float* __restrict__ xmean, float* __restrict__ o32,
                       u16* __restrict__ obf, float* __restrict__ gf) {
  int i = blockIdx.x * 256 + threadIdx.x;
  if (i < TR_) inv[index[i]] = i;
  if (i < 6144) xmean[i] = 0.f;
  if (i < 336) gf[(size_t)NTOK_ * 8 + i] = 0.f;         // pad-row gates
  o32[(size_t)NTOK_ * S_ + i] = 0.f;                    // pad rows (also zbuf init)
  obf[(size_t)NTOK_ * S_ + i] = 0;                      // GEMM1 A pad rows
}

// ---------- xmean ----------
__global__ void k_reduce_x(const float* __restrict__ x, float* __restrict__ xmean) {
  int i = blockIdx.x * 256 + threadIdx.x;
  int b = i / 3072, d = i % 3072;
  int s0 = blockIdx.y * 224;
  const float* p = x + (size_t)b * S_ * 3072 + (size_t)s0 * 3072 + d;
  float s = 0.f;
  for (int t = 0; t < 224; ++t) s += p[(size_t)t * 3072];
  atomicAdd(&xmean[i], s * (1.f / (float)S_));
}

// ---------- small gating ----------
__global__ __launch_bounds__(256)
void k_small_gates(const float* __restrict__ xmean,
                   const float* __restrict__ Wsel, const float* __restrict__ bsel,
                   const float* __restrict__ emb,  const float* __restrict__ Wemb,
                   const float* __restrict__ bemb,
                   float* __restrict__ w2buf, float* __restrict__ zpart,
                   float* __restrict__ outw) {
  __shared__ float red[256];
  __shared__ float gl[16];
  __shared__ float el[8];
  int tid = threadIdx.x;
  for (int o = 0; o < 16; ++o) {
    int b = o >> 3, g = o & 7;
    float s = 0.f;
    for (int d = tid; d < 3072; d += 256) s += xmean[b * 3072 + d] * Wsel[d * 8 + g];
    red[tid] = s; __syncthreads();
    for (int st = 128; st > 0; st >>= 1) { if (tid < st) red[tid] += red[tid + st]; __syncthreads(); }
    if (tid == 0) gl[o] = red[0] + bsel[g];
    __syncthreads();
  }
  for (int g = 0; g < 8; ++g) {
    float s = 0.f;
    for (int d = tid; d < 1536; d += 256) s += emb[d] * Wemb[d * 8 + g];
    red[tid] = s; __syncthreads();
    for (int st = 128; st > 0; st >>= 1) { if (tid < st) red[tid] += red[tid + st]; __syncthreads(); }
    if (tid == 0) el[g] = red[0] + bemb[g];
    __syncthreads();
  }
  if (tid == 0) {
    float zp = 0.f;
    for (int i = 0; i < 4; ++i) {
      float e0 = el[2 * i], e1 = el[2 * i + 1];
      float m = fmaxf(e0, e1);
      float x0 = expf(e0 - m), x1 = expf(e1 - m);
      float den = x0 + x1;
      float se0 = x0 / den, se1 = x1 / den;
      zp += (e0 * e0 + e1 * e1) * 0.5f;
      float tsq = 0.f;
      for (int b = 0; b < 2; ++b) {
        float t0 = gl[b * 8 + 2 * i], t1 = gl[b * 8 + 2 * i + 1];
        tsq += t0 * t0 + t1 * t1;
        float mm = fmaxf(t0, t1);
        float y0 = expf(t0 - mm), y1 = expf(t1 - mm);
        float dd = y0 + y1;
        float w0 = (y0 / dd + se0) * 0.5f, w1 = (y1 / dd + se1) * 0.5f;
        w2buf[b * 8 + 2 * i] = w0; w2buf[b * 8 + 2 * i + 1] = w1;
        outw[b * 8 + 2 * i]  = w0; outw[b * 8 + 2 * i + 1]  = w1;
      }
      zp += tsq * 0.25f;
    }
    *zpart = zp;
  }
}

// ---------- gather (round-11: LDS-tiled transpose, both sides coalesced) ----------
// tile 32(tr) x 32(s): read out_in[(b,s),tr] coalesced over contiguous tr;
// write o32/obf row inv[tr] coalesced over s (128B rows at scattered offsets).
__global__ __launch_bounds__(256)
void k_gather(const float* __restrict__ out_in, const int* __restrict__ inv,
              float* __restrict__ o32, u16* __restrict__ obf) {
  __shared__ float tile[32][33];
  int b = blockIdx.z;
  int tr0 = blockIdx.x * 32, s0 = blockIdx.y * 32;
  int tx = threadIdx.x & 31, ty = threadIdx.x >> 5;
  int ntr = TR_ - tr0; if (ntr > 32) ntr = 32;
  for (int i = ty; i < 32; i += 8)
    tile[i][tx] = (tx < ntr) ? out_in[((size_t)b * S_ + s0 + i) * TR_ + tr0 + tx] : 0.f;
  __syncthreads();
  for (int r = ty; r < ntr; r += 8) {
    int t = inv[tr0 + r];
    size_t off = ((size_t)b * TR_ + t) * S_ + s0 + tx;
    float v = tile[tx][r];
    o32[off] = v;
    obf[off] = f2bf(v);
  }
}

// ---------- per-token gating (no atomics, round-7 fix) ----------
__global__ __launch_bounds__(256)
void k_gates(const float* __restrict__ o32, const float* __restrict__ temb,
             const float* __restrict__ Wg, const float* __restrict__ bg,
             const float* __restrict__ w2buf, float* __restrict__ gf,
             float* __restrict__ zbuf) {
  int n = blockIdx.x;
  int b = n / TR_, t = n % TR_;
  int typ = (t < 228) ? 0 : (t < 519) ? 1 : (t < 1286) ? 2 : 3;
  int tid = threadIdx.x;
  const float* orow = o32 + (size_t)n * S_;
  const float* trow = temb + typ * S_;
  const float* W0 = Wg + (size_t)(2 * typ) * S_ * 8;

  float acc[16];
#pragma unroll
  for (int k = 0; k < 16; ++k) acc[k] = 0.f;
  for (int s = tid; s < S_; s += 256) {
    float ov = orow[s] + trow[s];
    const float4* wa = (const float4*)(W0 + s * 8);
    const float4* wb = (const float4*)(W0 + 7168 + s * 8);
    float4 a0 = wa[0], a1 = wa[1], b0 = wb[0], b1 = wb[1];
    acc[0]  += ov * a0.x; acc[1]  += ov * a0.y; acc[2]  += ov * a0.z; acc[3]  += ov * a0.w;
    acc[4]  += ov * a1.x; acc[5]  += ov * a1.y; acc[6]  += ov * a1.z; acc[7]  += ov * a1.w;
    acc[8]  += ov * b0.x; acc[9]  += ov * b0.y; acc[10] += ov * b0.z; acc[11] += ov * b0.w;
    acc[12] += ov * b1.x; acc[13] += ov * b1.y; acc[14] += ov * b1.z; acc[15] += ov * b1.w;
  }
#pragma unroll
  for (int k = 0; k < 16; ++k)
#pragma unroll
    for (int m = 1; m < 64; m <<= 1) acc[k] += __shfl_xor(acc[k], m, 64);

  __shared__ float wsum[4][16];
  __shared__ float lgsh[16];
  int w = tid >> 6, lane = tid & 63;
  if (lane == 0)
#pragma unroll
    for (int k = 0; k < 16; ++k) wsum[w][k] = acc[k];
  __syncthreads();
  if (tid < 16)
    lgsh[tid] = wsum[0][tid] + wsum[1][tid] + wsum[2][tid] + wsum[3][tid]
              + bg[(2 * typ + (tid >> 3)) * 8 + (tid & 7)];
  __syncthreads();

  if (tid == 0) {
    float g[8];
    for (int k = 0; k < 8; ++k) g[k] = 0.f;
    float zs[2];
    for (int j = 0; j < 2; ++j) {
      float l[8]; float ss = 0.f;
      for (int k = 0; k < 8; ++k) {
        float v = lgsh[j * 8 + k];
        v = v > 0.f ? v : 0.01f * v;
        l[k] = v; ss += v * v;
      }
      zs[j] = ss;
      int i0 = 0;
      for (int k = 1; k < 8; ++k) if (l[k] > l[i0]) i0 = k;
      int i1 = -1;
      for (int k = 0; k < 8; ++k) { if (k == i0) continue; if (i1 < 0 || l[k] > l[i1]) i1 = k; }
      int i2 = -1;
      for (int k = 0; k < 8; ++k) { if (k == i0 || k == i1) continue; if (i2 < 0 || l[k] > l[i2]) i2 = k; }
      float p1 = expf(l[i1] - l[i0]), p2 = expf(l[i2] - l[i0]);
      float den = 1.f + p1 + p2;
      float w2 = w2buf[b * 8 + 2 * typ + j];
      g[i0] += w2 / den; g[i1] += w2 * p1 / den; g[i2] += w2 * p2 / den;
    }
    float* gfp = gf + (size_t)n * 8;
    for (int k = 0; k < 8; ++k) gfp[k] = g[k];
    zbuf[n * 2 + 0] = zs[0];
    zbuf[n * 2 + 1] = zs[1];
  }
}

// ---------- segment reductions ----------
__global__ __launch_bounds__(256)
void k_reduce_gates(const float* __restrict__ gf, const float* __restrict__ zbuf,
                    float* __restrict__ allg, float* __restrict__ zsum) {
  __shared__ float red[256];
  const int s0a[4] = {0, 228, 519, 1286};
  const int cta[4] = {228, 291, 767, 357};
  int blk = blockIdx.x, tid = threadIdx.x;
  float s = 0.f;
  if (blk < 32) {
    int typ = blk >> 3, e = blk & 7;
    int s0 = s0a[typ], cnt = cta[typ];
    for (int i = tid; i < 2 * cnt; i += 256) {
      int bb = i / cnt, tt = s0 + i % cnt;
      s += gf[(size_t)(bb * TR_ + tt) * 8 + e];
    }
  } else {
    int idx = blk - 32, typ = idx >> 1, j = idx & 1;
    int s0 = s0a[typ], cnt = cta[typ];
    for (int i = tid; i < 2 * cnt; i += 256) {
      int bb = i / cnt, tt = s0 + i % cnt;
      s += zbuf[(size_t)(bb * TR_ + tt) * 2 + j];
    }
  }
  red[tid] = s; __syncthreads();
  for (int st = 128; st > 0; st >>= 1) { if (tid < st) red[tid] += red[tid + st]; __syncthreads(); }
  if (tid == 0) {
    if (blk < 32) allg[blk] = red[0];
    else          zsum[blk - 32] = red[0];
  }
}

// ---------- tiled transpose f32 -> bf16 with output-row padding ----------
__global__ __launch_bounds__(256)
void k_transpose(const float* __restrict__ W, u16* __restrict__ Wt,
                 int R, int C, int ldo, size_t eo) {
  __shared__ float tile[32][33];
  int e = blockIdx.z;
  const float* Wp = W + (size_t)e * R * C;
  u16* Wtp = Wt + (size_t)e * eo;
  int c0 = blockIdx.x * 32, r0 = blockIdx.y * 32;
  int tx = threadIdx.x & 31, ty = threadIdx.x >> 5;
  for (int i = ty; i < 32; i += 8)
    tile[i][tx] = (c0 + tx < C) ? Wp[(size_t)(r0 + i) * C + c0 + tx] : 0.f;
  __syncthreads();
  for (int i = ty; i < 32; i += 8) Wtp[(size_t)(c0 + i) * ldo + r0 + tx] = f2bf(tile[tx][i]);
}

// ---------- 256x256x64 8-wave COUNTED-VMCNT phase GEMM (round-9 schedule, verbatim) ----------
// Round-10's read-ahead variant REGRESSED (129.7 -> 187.4 us); this is the
// known-good schedule: per phase [counted PSYNC; stage issue; reads; MFMA],
// vmcnt(4)/(6)/(6), peel 4/2/0 — pipe never drains in the main loop.
template <int MODE>
__global__ __launch_bounds__(512, 2)
void k_gemm8(const u16* __restrict__ A, const u16* __restrict__ Bt,
             int K, int lda, int ldb,
             const float* __restrict__ gf, const float* __restrict__ bias,
             u16* __restrict__ H, float* __restrict__ ypart, int P) {
  __shared__ __align__(16) u16 lds[2 * 32768];   // [buf][A:16384|B:16384] u16
  const int tid = threadIdx.x;
  const int lane = tid & 63;
  const int wid = tid >> 6;
  const int wr = wid >> 2, wc = wid & 3;

  int bx, by, bz = 0;
  if (MODE == 1) {
    int f = blockIdx.y * 56 + blockIdx.x;            // 728 = 8*91
    f = (f & 7) * 91 + (f >> 3);
    by = f / 56; bx = f % 56;
  } else {
    int f = blockIdx.z * 52 + blockIdx.y * 4 + blockIdx.x;  // 52P, P even
    int n8 = (52 * P) >> 3;
    f = (f & 7) * n8 + (f >> 3);
    bz = f / 52; int r = f % 52;
    by = r / 4; bx = r % 4;
  }

  int kt0 = 0, ktN = K >> 6;
  if (MODE == 2) {
    int nt = K >> 6;
    kt0 = (bz * nt) / P; ktN = ((bz + 1) * nt) / P;
  }
  const int NT = ktN - kt0;

  const u16* Ag = A + (size_t)(by * 256) * lda;
  const u16* Bg = Bt + (size_t)(bx * 256) * ldb;

#define SA(buf, g, k0)                                                          \
  { _Pragma("unroll")                                                           \
    for (int q = 0; q < 2; ++q) {                                               \
      const int br = q * 128 + (g) * 64 + wid * 8;                              \
      const int row = br + (lane >> 3);                                         \
      gload16(Ag + (size_t)row * lda + (((lane & 7) ^ (lane >> 3)) << 3) + (k0),\
              lds + (buf) * 32768 + br * 64 + lane * 8);                        \
    } }
#define SB(buf, g, k0)                                                          \
  { _Pragma("unroll")                                                           \
    for (int q = 0; q < 2; ++q) {                                               \
      const int sI = q * 8 + wid;                                               \
      const int br = (sI >> 2) * 64 + (g) * 32 + (sI & 3) * 8;                  \
      const int row = br + (lane >> 3);                                         \
      gload16(Bg + (size_t)row * ldb + (((lane & 7) ^ (lane >> 3)) << 3) + (k0),\
              lds + (buf) * 32768 + 16384 + br * 64 + lane * 8);                \
    } }
#define PSYNC(N)                                             \
  asm volatile("s_waitcnt vmcnt(" #N ")" ::: "memory");      \
  __builtin_amdgcn_s_barrier();                              \
  __builtin_amdgcn_sched_barrier(0);

  const int l15 = lane & 15, l16 = lane >> 4, l7 = lane & 7;
  const int swz0 = (l16 ^ l7) << 3;
  const int swz1 = ((4 + l16) ^ l7) << 3;
  const int rA = (wr * 128 + l15) * 64;
  const int rB = (wc * 64 + l15) * 64;

  f32x4 acc[8][4] = {};
  bf16x8 aF[4][2], b0F[2][2], b1F[2][2];

#define READ_A0  _Pragma("unroll") for (int i = 0; i < 4; ++i) {               \
    aF[i][0] = *(const bf16x8*)(lA + rA + i * 1024 + swz0);                    \
    aF[i][1] = *(const bf16x8*)(lA + rA + i * 1024 + swz1); }
#define READ_A1  _Pragma("unroll") for (int i = 0; i < 4; ++i) {               \
    aF[i][0] = *(const bf16x8*)(lA + rA + (i + 4) * 1024 + swz0);              \
    aF[i][1] = *(const bf16x8*)(lA + rA + (i + 4) * 1024 + swz1); }
#define READ_B0  _Pragma("unroll") for (int j = 0; j < 2; ++j) {               \
    b0F[j][0] = *(const bf16x8*)(lB + rB + j * 1024 + swz0);                   \
    b0F[j][1] = *(const bf16x8*)(lB + rB + j * 1024 + swz1); }
#define READ_B1  _Pragma("unroll") for (int j = 0; j < 2; ++j) {               \
    b1F[j][0] = *(const bf16x8*)(lB + rB + (j + 2) * 1024 + swz0);             \
    b1F[j][1] = *(const bf16x8*)(lB + rB + (j + 2) * 1024 + swz1); }
#define MFMA16(IB, JB, BF)                                                     \
  __builtin_amdgcn_s_setprio(1);                                               \
  _Pragma("unroll") for (int i = 0; i < 4; ++i)                                \
  _Pragma("unroll") for (int j = 0; j < 2; ++j) {                              \
    acc[i + IB][j + JB] = __builtin_amdgcn_mfma_f32_16x16x32_bf16(aF[i][0], BF[j][0], acc[i + IB][j + JB], 0, 0, 0); \
    acc[i + IB][j + JB] = __builtin_amdgcn_mfma_f32_16x16x32_bf16(aF[i][1], BF[j][1], acc[i + IB][j + JB], 0, 0, 0); \
  }                                                                            \
  __builtin_amdgcn_s_setprio(0);

  // prologue: tile kt0, issue order A0,B0,B1,A1 (oldest -> newest)
  { const int k0 = kt0 << 6; SA(0, 0, k0) SB(0, 0, k0) SB(0, 1, k0) SA(0, 1, k0) }

  int cur = 0;
  for (int t = 0; t < NT - 1; ++t) {
    const u16* lA = lds + cur * 32768;
    const u16* lB = lA + 16384;
    const int nk0 = (kt0 + t + 1) << 6;
    // P1: wait A0,B0(t); issue A0,B0(t+1); Q00
    PSYNC(4)
    SA(cur ^ 1, 0, nk0) SB(cur ^ 1, 0, nk0)
    READ_A0 READ_B0
    MFMA16(0, 0, b0F)
    // P2: wait B1(t); issue B1(t+1); Q01
    PSYNC(6)
    SB(cur ^ 1, 1, nk0)
    READ_B1
    MFMA16(0, 2, b1F)
    // P3: wait A1(t); issue A1(t+1); Q11
    PSYNC(6)
    SA(cur ^ 1, 1, nk0)
    READ_A1
    MFMA16(4, 2, b1F)
    // P4: regs only; Q10
    MFMA16(4, 0, b0F)
    cur ^= 1;
  }
  // last tile: peel with draining waits
  {
    const u16* lA = lds + cur * 32768;
    const u16* lB = lA + 16384;
    PSYNC(4)
    READ_A0 READ_B0
    MFMA16(0, 0, b0F)
    PSYNC(2)
    READ_B1
    MFMA16(0, 2, b1F)
    PSYNC(0)
    READ_A1
    MFMA16(4, 2, b1F)
    MFMA16(4, 0, b0F)
  }
#undef SA
#undef SB
#undef PSYNC
#undef READ_A0
#undef READ_A1
#undef READ_B0
#undef READ_B1
#undef MFMA16

  // ---- epilogue ----
  if (MODE == 1) {
    const int e = bx / 7;                 // 1792 = 7*256: tile within one expert
#pragma unroll
    for (int j = 0; j < 4; ++j) {
      const int col = bx * 256 + wc * 64 + j * 16 + l15;
      const float bia = bias[col];
#pragma unroll
      for (int i = 0; i < 8; ++i)
#pragma unroll
        for (int r = 0; r < 4; ++r) {
          const int row = by * 256 + wr * 128 + i * 16 + l16 * 4 + r;
          float v = acc[i][j][r] + bia;
          v = v > 0.f ? v : 0.f;
          H[(size_t)row * 14336 + col] = f2bf(v * gf[row * 8 + e]);
        }
    }
  } else {
    float* yp = ypart + (size_t)bz * ((size_t)MP_ * 1024);
#pragma unroll
    for (int j = 0; j < 4; ++j) {
      const int col = bx * 256 + wc * 64 + j * 16 + l15;
#pragma unroll
      for (int i = 0; i < 8; ++i)
#pragma unroll
        for (int r = 0; r < 4; ++r) {
          const int row = by * 256 + wr * 128 + i * 16 + l16 * 4 + r;
          yp[(size_t)row * 1024 + col] = acc[i][j][r];
        }
    }
  }
}

// ---------- reduce split-K partials + gated b2 bias, TRANSPOSED output ----------
// Round-11: writes yT[b][s][t] via LDS 32x32 tile so k_scatter's random access
// is confined within one 6.6KB row (L1-resident) instead of random rows.
__global__ __launch_bounds__(256)
void k_reduce_yT(const float* __restrict__ yp, int P,
                 const float* __restrict__ gf, const float* __restrict__ b2,
                 float* __restrict__ yT) {
  __shared__ float tile[32][33];
  int b = blockIdx.z;
  int t0 = blockIdx.x * 32, s0 = blockIdx.y * 32;
  int tx = threadIdx.x & 31, ty = threadIdx.x >> 5;
  int ntv = TR_ - t0; if (ntv > 32) ntv = 32;
  for (int r = ty; r < 32; r += 8) {           // r over t
    float acc = 0.f;
    if (r < ntv) {
      size_t n = (size_t)b * TR_ + t0 + r;
      size_t base = n * 1024 + s0 + tx;
      for (int p = 0; p < P; ++p) acc += yp[(size_t)p * ((size_t)MP_ * 1024) + base];
      const float* g = gf + n * 8;
#pragma unroll
      for (int e = 0; e < 8; ++e) acc += g[e] * b2[e * S_ + s0 + tx];
    }
    tile[r][tx] = acc;
  }
  __syncthreads();
  for (int i = ty; i < 32; i += 8)             // i over s
    if (tx < ntv)
      yT[((size_t)b * S_ + s0 + i) * TR_ + t0 + tx] = tile[tx][i];
}

// ---------- scatter: dout[b,s,tr] = out[b,s,tr] + yT[b,s,inv[tr]] ----------
__global__ void k_scatter(const float* __restrict__ yT, const float* __restrict__ out_in,
                          const int* __restrict__ inv, float* __restrict__ dout) {
  int i = blockIdx.x * 256 + threadIdx.x;   // < B*S*TR = 2944256
  int tr = i % TR_;
  dout[i] = out_in[i] + yT[(size_t)(i - tr) + inv[tr]];
}

// ---------- finalize ----------
__global__ void k_finalize(const float* __restrict__ allg, const float* __restrict__ zsum,
                           const float* __restrict__ zpart, float* __restrict__ dout) {
  int tid = threadIdx.x;
  if (tid < 32) dout[2944256 + tid] = allg[tid];
  if (tid == 32) {
    float z = *zpart;
    const int Ts[4] = {228, 291, 767, 357};
    for (int i = 0; i < 4; ++i)
      for (int j = 0; j < 2; ++j)
        z += zsum[i * 2 + j] / (float)(2 * Ts[i] * 8);
    dout[2944288] = z;
    dout[2944289] = 0.f;
  }
}

extern "C" void kernel_launch(void* const* d_in, const int* in_sizes, int n_in,
                              void* d_out, int out_size, void* d_ws, size_t ws_size,
                              hipStream_t stream) {
  const float* x         = (const float*)d_in[0];
  const float* out_in    = (const float*)d_in[1];
  const float* embedding = (const float*)d_in[2];
  const int*   index     = (const int*)d_in[3];
  const float* Wsel      = (const float*)d_in[4];
  const float* bsel      = (const float*)d_in[5];
  const float* Wemb      = (const float*)d_in[6];
  const float* bemb      = (const float*)d_in[7];
  const float* Wg        = (const float*)d_in[8];
  const float* bg        = (const float*)d_in[9];
  const float* temb      = (const float*)d_in[10];
  const float* W1        = (const float*)d_in[11];
  const float* b1        = (const float*)d_in[12];
  const float* W2        = (const float*)d_in[13];
  const float* b2        = (const float*)d_in[14];
  float* dout = (float*)d_out;

  char* ws = (char*)d_ws;
  float* allg  = (float*)(ws + 0);
  float* zsum  = (float*)(ws + 128);
  float* zpart = (float*)(ws + 160);
  float* w2buf = (float*)(ws + 192);
  int*   inv   = (int*)(ws + 256);
  float* xmean = (float*)(ws + 8192);
  float* gf    = (float*)(ws + 32768);       // MP*8 f        -> ends 139264
  float* o32   = (float*)(ws + 139264);      // MP*896 f      -> ends 12066816 (reused as yT)
  float* yT    = o32;                        // dead after k_gates; exactly NTOK_*S_ floats used
  float* zbuf  = (float*)(ws + 139264 + (size_t)NTOK_ * S_ * 4);  // pad-row overlay
  u16*   obf   = (u16*)(ws + 12066816);      // MP*896 bf16   -> ends 18030592
  u16*   w1t   = (u16*)(ws + 18030592);      // 14336*896 bf16 -> ends 43720704
  u16*   w2t   = (u16*)(ws + 43720704);      // 1024*14336 bf16 (padded) -> ends 73080832
  u16*   Hb    = (u16*)(ws + 73080832);      // MP*14336 bf16  -> ends 168501248

  const size_t HIGH = 168501248ull, YPSZ = (size_t)MP_ * 1024 * 4;  // 13,631,488
  int P; float* ypart = (float*)(ws + HIGH);
  if      (ws_size >= HIGH + 8 * YPSZ) P = 8;
  else if (ws_size >= HIGH + 6 * YPSZ) P = 6;
  else if (ws_size >= HIGH + 4 * YPSZ) P = 4;
  else                                 P = 2;

  k_init<<<147, 256, 0, stream>>>(index, inv, xmean, o32, obf, gf);
  k_reduce_x<<<dim3(24, 4), 256, 0, stream>>>(x, xmean);
  k_small_gates<<<1, 256, 0, stream>>>(xmean, Wsel, bsel, embedding, Wemb, bemb,
                                       w2buf, zpart, dout + 2944290);
  k_gather<<<dim3(52, 28, 2), 256, 0, stream>>>(out_in, inv, o32, obf);
  k_gates<<<NTOK_, 256, 0, stream>>>(o32, temb, Wg, bg, w2buf, gf, zbuf);
  k_reduce_gates<<<40, 256, 0, stream>>>(gf, zbuf, allg, zsum);

  // GEMM1: H' = gf .* relu(obf @ W1^T + b1)   [M=3328, N=14336, K=896]
  k_transpose<<<dim3(56, 28, 8), 256, 0, stream>>>(W1, w1t, 896, 1792, 896, (size_t)1605632);
  k_gemm8<1><<<dim3(56, 13), 512, 0, stream>>>(
      obf, w1t, 896, 896, 896, gf, b1, Hb, nullptr, 0);

  // GEMM2: ypart[z] = H' @ W2flat^T chunk  [M=3328, N=896(pad 1024), K=14336 split-P]
  k_transpose<<<dim3(32, 56, 8), 256, 0, stream>>>(W2, w2t, 1792, 896, 14336, (size_t)1792);
  k_gemm8<2><<<dim3(4, 13, P), 512, 0, stream>>>(
      Hb, w2t, 14336, 14336, 14336, nullptr, nullptr, nullptr, ypart, P);
  k_reduce_yT<<<dim3(52, 28, 2), 256, 0, stream>>>(ypart, P, gf, b2, yT);

  k_scatter<<<11501, 256, 0, stream>>>(yT, out_in, inv, dout);
  k_finalize<<<1, 64, 0, stream>>>(allg, zsum, zpart, dout);
}